// Round 11
// baseline (214.406 us; speedup 1.0000x reference)
//
#include <hip/hip_runtime.h>
#include <hip/hip_bf16.h>
#include <math.h>

typedef __attribute__((ext_vector_type(8))) __bf16 bf16x8;
typedef __attribute__((ext_vector_type(4))) float f32x4;
typedef __attribute__((ext_vector_type(4))) unsigned int u32x4;

#define DIM 1024
#define SEQ 2048
#define BATCH 4
#define ROWS (BATCH*SEQ)

#define BAR() do { asm volatile("" ::: "memory"); __builtin_amdgcn_s_barrier(); asm volatile("" ::: "memory"); } while(0)
#define WAITV(n) asm volatile("s_waitcnt vmcnt(" #n ")" ::: "memory")
#define WAITL(n) asm volatile("s_waitcnt lgkmcnt(" #n ")" ::: "memory")
#define SCHED0() __builtin_amdgcn_sched_barrier(0)
#define PRIO(x) __builtin_amdgcn_s_setprio(x)

// inline-asm LDS read: escapes auto-waitcnt; ordered manually via WAITL/WAITV.
#define DSR(d, a, off) do { u32x4 _t; \
  asm volatile("ds_read_b128 %0, %1 offset:" #off : "=v"(_t) : "v"(a)); \
  (d) = __builtin_bit_cast(bf16x8, _t); } while(0)

__device__ __forceinline__ unsigned short f2bf(float f) {
  unsigned int u = __float_as_uint(f);
  u += 0x7FFF + ((u >> 16) & 1);   // RNE
  return (unsigned short)(u >> 16);
}

__device__ __forceinline__ void gload_lds16(const void* g, void* lds) {
  __builtin_amdgcn_global_load_lds((__attribute__((address_space(1))) void*)g,
                                   (__attribute__((address_space(3))) void*)lds,
                                   16, 0, 0);
}

// ---------- f32 -> bf16 ----------
__global__ __launch_bounds__(256)
void conv_f32_bf16(const float* __restrict__ src, unsigned short* __restrict__ dst, int n8) {
  int i = blockIdx.x * blockDim.x + threadIdx.x;
  if (i >= n8) return;
  const float4* s = reinterpret_cast<const float4*>(src) + (size_t)i * 2;
  float4 a = s[0], b = s[1];
  union { unsigned short h[8]; uint4 v; } p;
  p.h[0]=f2bf(a.x); p.h[1]=f2bf(a.y); p.h[2]=f2bf(a.z); p.h[3]=f2bf(a.w);
  p.h[4]=f2bf(b.x); p.h[5]=f2bf(b.y); p.h[6]=f2bf(b.z); p.h[7]=f2bf(b.w);
  reinterpret_cast<uint4*>(dst)[i] = p.v;
}

// ---------- merged weight transpose: z=0..2 -> W_in col-chunks, z=3 -> W_out ----------
__global__ __launch_bounds__(1024)
void transpose_weights(const float* __restrict__ W_in, unsigned short* __restrict__ WinT,
                       const float* __restrict__ W_out, unsigned short* __restrict__ WoutT) {
  __shared__ unsigned short tile[32][33];
  const int z = blockIdx.z;
  const float* src; unsigned short* dst; int ldsrc, bx;
  if (z < 3) { src = W_in;  dst = WinT;  ldsrc = 3 * DIM; bx = z * 32 + blockIdx.x; }
  else       { src = W_out; dst = WoutT; ldsrc = DIM;     bx = blockIdx.x; }
  int tx = threadIdx.x, ty = threadIdx.y;
  int r = blockIdx.y * 32 + ty, c = bx * 32 + tx;
  tile[ty][tx] = f2bf(src[(size_t)r * ldsrc + c]);
  __syncthreads();
  dst[(size_t)(bx * 32 + ty) * DIM + blockIdx.y * 32 + tx] = tile[tx][ty];
}

#define EPI_QKV 0
#define EPI_F32 1
#define EPI_BF16 2
#define EPI_BIAS_F32 3

// ---------- phased NT GEMM: C[M,N] = A[M,K]*B[N,K]^T ----------
// BM=256, BK=64, 8 waves (2M x 4N), per-wave 128 x (BN/4).
// BN=256: lgkm-counted prefetch rhythm (round-6, fastest for scores).
// BN=128: round-4 4-phase kk-split (fastest for QKV/PV/proj).
// No XCD swizzle (measured: +5us / +9MB FETCH on QKV — reverted).
// EPI_QKV: V-column blocks (tileN>=2*DIM) write transposed directly to Vt.
template<int BN, int EPI>
__global__ __launch_bounds__(512, 2)
void gemm8(const unsigned short* __restrict__ A, int lda, size_t sA,
           const unsigned short* __restrict__ B, int ldb, size_t sB,
           void* __restrict__ C, int ldc, size_t sC,
           const float* __restrict__ bias, int K,
           unsigned short* __restrict__ VtOut, size_t sVt) {
  constexpr int NREP = BN / 64;     // 4 or 2
  constexpr int NW = 16 * NREP;     // 64 or 32
  __shared__ unsigned short As[2 * 256 * 64];
  __shared__ unsigned short Bs[2 * BN * 64];

  const int tid = threadIdx.x;
  const int lane = tid & 63, wave = tid >> 6;
  const int wm = wave >> 2, wn = wave & 3;
  const int fr = lane & 15, fk = lane >> 4;
  const int tileM = blockIdx.y * 256, tileN = blockIdx.x * BN;
  const unsigned short* Ab = A + (size_t)blockIdx.z * sA;
  const unsigned short* Bb = B + (size_t)blockIdx.z * sB;

  const int srow = tid >> 3;
  const int sg = (tid & 7) ^ (srow & 7);     // pre-swizzled source 16B-chunk

  auto stageA = [&](int buf, int half, int k0) {
#pragma unroll
    for (int q = 0; q < 2; ++q) {
      int rl = half * 128 + q * 64 + srow;
      gload_lds16(Ab + (size_t)(tileM + rl) * lda + k0 + sg * 8,
                  &As[buf * (256 * 64) + rl * 64 + (tid & 7) * 8]);
    }
  };
  auto stageB = [&](int buf, int half, int k0) {
#pragma unroll
    for (int q = 0; q < 2; ++q) {
      int rl = half * 128 + q * 64 + srow;
      gload_lds16(Bb + (size_t)(tileN + rl) * ldb + k0 + sg * 8,
                  &Bs[buf * (BN * 64) + rl * 64 + (tid & 7) * 8]);
    }
  };

  f32x4 acc[8][NREP];
#pragma unroll
  for (int m = 0; m < 8; ++m)
#pragma unroll
    for (int n = 0; n < NREP; ++n) acc[m][n] = (f32x4){0.f, 0.f, 0.f, 0.f};

  const int NS = K >> 6;
  const unsigned asb = (unsigned)(size_t)(__attribute__((address_space(3))) unsigned short*)As;
  const unsigned bsb = (unsigned)(size_t)(__attribute__((address_space(3))) unsigned short*)Bs;
  const unsigned aoff = (unsigned)((wm * 128 + fr) * 128 + ((fk ^ (fr & 7)) << 4));
  const unsigned boff = (unsigned)((wn * NW + fr) * 128 + ((fk ^ (fr & 7)) << 4));
  auto aBase = [&](int b) { return asb + (unsigned)b * 32768u + aoff; };
  auto bBase = [&](int b) { return bsb + (unsigned)b * (unsigned)(BN * 128) + boff; };

  if constexpr (BN == 256) {
    bf16x8 afLo[4][2], afHi[4][2], bgA[2][2], bgB[2][2];
    stageB(0, 0, 0); stageB(0, 1, 0); stageA(0, 0, 0); stageA(0, 1, 0);
    if (NS > 1) { stageB(1, 0, 64); stageB(1, 1, 64); WAITV(4); } else { WAITV(0); }
    BAR();
    {
      unsigned a0 = aBase(0), a1 = a0 ^ 64u, b0 = bBase(0), b1 = b0 ^ 64u;
      DSR(afLo[0][0], a0, 0); DSR(afLo[1][0], a0, 2048); DSR(afLo[2][0], a0, 4096); DSR(afLo[3][0], a0, 6144);
      DSR(afLo[0][1], a1, 0); DSR(afLo[1][1], a1, 2048); DSR(afLo[2][1], a1, 4096); DSR(afLo[3][1], a1, 6144);
      DSR(bgA[0][0], b0, 0); DSR(bgA[1][0], b0, 2048);
      DSR(bgA[0][1], b1, 0); DSR(bgA[1][1], b1, 2048);
    }
    for (int t = 0; t < NS; ++t) {
      const int cb = t & 1, nb = cb ^ 1;
      const unsigned cA0 = aBase(cb), cA1 = cA0 ^ 64u, cB0 = bBase(cb), cB1 = cB0 ^ 64u;
      const unsigned nA0 = aBase(nb), nA1 = nA0 ^ 64u, nB0 = bBase(nb), nB1 = nB0 ^ 64u;
      const int k1 = (t + 1) << 6, k2 = (t + 2) << 6;
      DSR(bgB[0][0], cB0, 4096); DSR(bgB[1][0], cB0, 6144);
      DSR(bgB[0][1], cB1, 4096); DSR(bgB[1][1], cB1, 6144);
      if (t + 1 < NS) stageA(nb, 0, k1);
      BAR(); WAITL(4); SCHED0();
      PRIO(1);
#pragma unroll
      for (int kk = 0; kk < 2; ++kk)
#pragma unroll
        for (int m = 0; m < 4; ++m)
#pragma unroll
          for (int n = 0; n < 2; ++n)
            acc[m][n] = __builtin_amdgcn_mfma_f32_16x16x32_bf16(afLo[m][kk], bgA[n][kk], acc[m][n], 0, 0, 0);
      PRIO(0); SCHED0();
      BAR();
      DSR(afHi[0][0], cA0, 8192); DSR(afHi[1][0], cA0, 10240); DSR(afHi[2][0], cA0, 12288); DSR(afHi[3][0], cA0, 14336);
      DSR(afHi[0][1], cA1, 8192); DSR(afHi[1][1], cA1, 10240); DSR(afHi[2][1], cA1, 12288); DSR(afHi[3][1], cA1, 14336);
      if (t + 1 < NS) stageA(nb, 1, k1);
      if (t + 2 < NS) stageB(cb, 0, k2);
      BAR(); WAITL(8); SCHED0();
      PRIO(1);
#pragma unroll
      for (int kk = 0; kk < 2; ++kk)
#pragma unroll
        for (int m = 0; m < 4; ++m)
#pragma unroll
          for (int n = 0; n < 2; ++n)
            acc[m][2 + n] = __builtin_amdgcn_mfma_f32_16x16x32_bf16(afLo[m][kk], bgB[n][kk], acc[m][2 + n], 0, 0, 0);
      PRIO(0); SCHED0();
      BAR();
      if (t + 2 < NS) stageB(cb, 1, k2);
      BAR(); WAITL(0); SCHED0();
      PRIO(1);
#pragma unroll
      for (int kk = 0; kk < 2; ++kk)
#pragma unroll
        for (int m = 0; m < 4; ++m)
#pragma unroll
          for (int n = 0; n < 2; ++n)
            acc[4 + m][n] = __builtin_amdgcn_mfma_f32_16x16x32_bf16(afHi[m][kk], bgA[n][kk], acc[4 + m][n], 0, 0, 0);
      PRIO(0); SCHED0();
      if (t + 1 < NS) { if (t + 2 < NS) { WAITV(4); } else { WAITV(0); } }
      BAR();
      if (t + 1 < NS) {
        DSR(afLo[0][0], nA0, 0); DSR(afLo[1][0], nA0, 2048); DSR(afLo[2][0], nA0, 4096); DSR(afLo[3][0], nA0, 6144);
        DSR(afLo[0][1], nA1, 0); DSR(afLo[1][1], nA1, 2048); DSR(afLo[2][1], nA1, 4096); DSR(afLo[3][1], nA1, 6144);
        DSR(bgA[0][0], nB0, 0); DSR(bgA[1][0], nB0, 2048);
        DSR(bgA[0][1], nB1, 0); DSR(bgA[1][1], nB1, 2048);
      }
      SCHED0();
      PRIO(1);
#pragma unroll
      for (int kk = 0; kk < 2; ++kk)
#pragma unroll
        for (int m = 0; m < 4; ++m)
#pragma unroll
          for (int n = 0; n < 2; ++n)
            acc[4 + m][2 + n] = __builtin_amdgcn_mfma_f32_16x16x32_bf16(afHi[m][kk], bgB[n][kk], acc[4 + m][2 + n], 0, 0, 0);
      PRIO(0); SCHED0();
      BAR();
    }
  } else {
    bf16x8 afLo[4][2], afHi[4][2], bgA[2][2];
    stageB(0, 0, 0); stageA(0, 0, 0); stageA(0, 1, 0);
    if (NS > 1) { stageB(1, 0, 64); WAITV(2); } else { WAITV(0); }
    BAR();
    for (int t = 0; t < NS; ++t) {
      const int cb = t & 1, nb = cb ^ 1;
      const unsigned aA0 = aBase(cb), aA1 = aA0 ^ 64u;
      const unsigned bB0 = bBase(cb), bB1 = bB0 ^ 64u;
      const int k1 = (t + 1) << 6, k2 = (t + 2) << 6;
      DSR(afLo[0][0], aA0, 0); DSR(afLo[1][0], aA0, 2048); DSR(afLo[2][0], aA0, 4096); DSR(afLo[3][0], aA0, 6144);
      DSR(bgA[0][0], bB0, 0); DSR(bgA[1][0], bB0, 2048);
      if (t + 1 < NS) stageA(nb, 0, k1);
      BAR(); WAITL(0); SCHED0();
      PRIO(1);
#pragma unroll
      for (int m = 0; m < 4; ++m)
#pragma unroll
        for (int n = 0; n < 2; ++n)
          acc[m][n] = __builtin_amdgcn_mfma_f32_16x16x32_bf16(afLo[m][0], bgA[n][0], acc[m][n], 0, 0, 0);
      PRIO(0); SCHED0();
      BAR();
      DSR(afLo[0][1], aA1, 0); DSR(afLo[1][1], aA1, 2048); DSR(afLo[2][1], aA1, 4096); DSR(afLo[3][1], aA1, 6144);
      DSR(bgA[0][1], bB1, 0); DSR(bgA[1][1], bB1, 2048);
      if (t + 1 < NS) stageA(nb, 1, k1);
      BAR(); WAITL(0); SCHED0();
      PRIO(1);
#pragma unroll
      for (int m = 0; m < 4; ++m)
#pragma unroll
        for (int n = 0; n < 2; ++n)
          acc[m][n] = __builtin_amdgcn_mfma_f32_16x16x32_bf16(afLo[m][1], bgA[n][1], acc[m][n], 0, 0, 0);
      PRIO(0); SCHED0();
      BAR();
      DSR(afHi[0][0], aA0, 8192); DSR(afHi[1][0], aA0, 10240); DSR(afHi[2][0], aA0, 12288); DSR(afHi[3][0], aA0, 14336);
      DSR(afHi[0][1], aA1, 8192); DSR(afHi[1][1], aA1, 10240); DSR(afHi[2][1], aA1, 12288); DSR(afHi[3][1], aA1, 14336);
      if (t + 2 < NS) stageB(cb, 0, k2);
      BAR(); WAITL(0); SCHED0();
      PRIO(1);
#pragma unroll
      for (int m = 0; m < 4; ++m)
#pragma unroll
        for (int n = 0; n < 2; ++n)
          acc[4 + m][n] = __builtin_amdgcn_mfma_f32_16x16x32_bf16(afHi[m][0], bgA[n][0], acc[4 + m][n], 0, 0, 0);
      PRIO(0); SCHED0();
      BAR();
      PRIO(1);
#pragma unroll
      for (int m = 0; m < 4; ++m)
#pragma unroll
        for (int n = 0; n < 2; ++n)
          acc[4 + m][n] = __builtin_amdgcn_mfma_f32_16x16x32_bf16(afHi[m][1], bgA[n][1], acc[4 + m][n], 0, 0, 0);
      PRIO(0); SCHED0();
      if (t + 1 < NS) { if (t + 2 < NS) { WAITV(2); } else { WAITV(0); } }
      BAR();
    }
  }

  // ---- epilogue ----
  if (EPI == EPI_QKV && tileN >= 2 * DIM) {
    // V block: write transposed directly into Vt[d][seq] (j is seq-contiguous)
    const int b = tileM >> 11;                 // batch (tileM multiple of 256)
    const int sb0 = (tileM & (SEQ - 1)) + wm * 128;
    unsigned short* Vb = VtOut + (size_t)b * sVt;
#pragma unroll
    for (int m = 0; m < 8; ++m)
#pragma unroll
      for (int n = 0; n < NREP; ++n) {
        int col = tileN + wn * NW + n * 16 + fr;
        int d = col - 2 * DIM;
        int s = sb0 + m * 16 + fk * 4;
        union { unsigned short h[4]; uint2 u; } p;
#pragma unroll
        for (int j = 0; j < 4; ++j) p.h[j] = f2bf(acc[m][n][j] + bias[col]);
        *reinterpret_cast<uint2*>(&Vb[(size_t)d * SEQ + s]) = p.u;
      }
  } else {
#pragma unroll
    for (int m = 0; m < 8; ++m)
#pragma unroll
      for (int n = 0; n < NREP; ++n)
#pragma unroll
        for (int j = 0; j < 4; ++j) {
          int row = tileM + wm * 128 + m * 16 + fk * 4 + j;
          int col = tileN + wn * NW + n * 16 + fr;
          float v = acc[m][n][j];
          if (EPI == EPI_QKV) {
            v += bias[col];
            if (col < DIM) v *= 0.03125f;   // 1/sqrt(1024)
            ((unsigned short*)C + (size_t)blockIdx.z * sC)[(size_t)row * ldc + col] = f2bf(v);
          } else if (EPI == EPI_BF16) {
            ((unsigned short*)C + (size_t)blockIdx.z * sC)[(size_t)row * ldc + col] = f2bf(v);
          } else if (EPI == EPI_BIAS_F32) {
            ((float*)C + (size_t)blockIdx.z * sC)[(size_t)row * ldc + col] = v + bias[col];
          } else {
            ((float*)C + (size_t)blockIdx.z * sC)[(size_t)row * ldc + col] = v;
          }
        }
  }
}

// ---------- row softmax, in-place: fp32 row -> bf16 P at row start ----------
__global__ __launch_bounds__(256)
void softmax_kernel(float* __restrict__ S, size_t zstride) {
  __shared__ float red[8];
  float* row = S + (size_t)blockIdx.y * zstride + (size_t)blockIdx.x * SEQ;
  const int tid = threadIdx.x;
  const int lane = tid & 63, wave = tid >> 6;
  const float4* src = reinterpret_cast<const float4*>(row) + tid * 2;
  float4 a = src[0], b = src[1];
  float v[8] = {a.x, a.y, a.z, a.w, b.x, b.y, b.z, b.w};
  float m = v[0];
#pragma unroll
  for (int i = 1; i < 8; ++i) m = fmaxf(m, v[i]);
  for (int o = 32; o; o >>= 1) m = fmaxf(m, __shfl_xor(m, o));
  if (lane == 0) red[wave] = m;
  __syncthreads();
  m = fmaxf(fmaxf(red[0], red[1]), fmaxf(red[2], red[3]));
  float e[8], s = 0.f;
#pragma unroll
  for (int i = 0; i < 8; ++i) { e[i] = __expf(v[i] - m); s += e[i]; }
  for (int o = 32; o; o >>= 1) s += __shfl_xor(s, o);
  if (lane == 0) red[4 + wave] = s;
  __syncthreads();
  s = red[4] + red[5] + red[6] + red[7];
  float inv = 1.f / s;
  union { unsigned short h[8]; uint4 u; } p;
#pragma unroll
  for (int i = 0; i < 8; ++i) p.h[i] = f2bf(e[i] * inv);
  reinterpret_cast<uint4*>(row)[tid] = p.u;
}

extern "C" void kernel_launch(void* const* d_in, const int* in_sizes, int n_in,
                              void* d_out, int out_size, void* d_ws, size_t ws_size,
                              hipStream_t stream) {
  const float* X     = (const float*)d_in[0];
  const float* W_in  = (const float*)d_in[1];
  const float* b_in  = (const float*)d_in[2];
  const float* W_out = (const float*)d_in[3];
  const float* b_out = (const float*)d_in[4];
  float* out = (float*)d_out;
  char* ws = (char*)d_ws;

  size_t o = 0;
  auto alloc = [&](size_t bytes) { size_t r = o; o += (bytes + 255) & ~(size_t)255; return r; };
  unsigned short* Xbf   = (unsigned short*)(ws + alloc((size_t)ROWS * DIM * 2));     // aliased as O later
  unsigned short* WinT  = (unsigned short*)(ws + alloc((size_t)3 * DIM * DIM * 2));
  unsigned short* WoutT = (unsigned short*)(ws + alloc((size_t)DIM * DIM * 2));
  unsigned short* QKV   = (unsigned short*)(ws + alloc((size_t)ROWS * 3 * DIM * 2));
  unsigned short* Vt    = (unsigned short*)(ws + alloc((size_t)BATCH * DIM * SEQ * 2)); // QKV fills all batches
  size_t fixed = o;
  size_t per_batch = (((size_t)SEQ * SEQ * 4 + 255) & ~(size_t)255);
  int G = (ws_size >= fixed + 4 * per_batch) ? BATCH : 1;
  float* Sc = (float*)(ws + alloc((size_t)G * SEQ * SEQ * 4));  // P written in place (bf16)
  unsigned short* Ob = Xbf;   // Xbf dead after QKV GEMM

  conv_f32_bf16<<<(ROWS * DIM / 8 + 255) / 256, 256, 0, stream>>>(X, Xbf, ROWS * DIM / 8);
  transpose_weights<<<dim3(32, 32, 4), dim3(32, 32), 0, stream>>>(W_in, WinT, W_out, WoutT);
  // QKV (Q,K into QKV buffer; V transposed directly into Vt)
  gemm8<128, EPI_QKV><<<dim3(3 * DIM / 128, ROWS / 256, 1), 512, 0, stream>>>(
      Xbf, DIM, 0, WinT, DIM, 0, QKV, 3 * DIM, 0, b_in, DIM,
      Vt, (size_t)DIM * SEQ);

  for (int b0 = 0; b0 < BATCH; b0 += G) {
    const unsigned short* Qb = QKV + (size_t)b0 * SEQ * 3 * DIM;
    const unsigned short* Kb = Qb + DIM;
    gemm8<256, EPI_F32><<<dim3(SEQ / 256, SEQ / 256, G), 512, 0, stream>>>(
        Qb, 3 * DIM, (size_t)SEQ * 3 * DIM, Kb, 3 * DIM, (size_t)SEQ * 3 * DIM,
        Sc, SEQ, (size_t)SEQ * SEQ, nullptr, DIM, nullptr, 0);
    softmax_kernel<<<dim3(SEQ, G), 256, 0, stream>>>(Sc, (size_t)SEQ * SEQ);
    gemm8<128, EPI_BF16><<<dim3(DIM / 128, SEQ / 256, G), 512, 0, stream>>>(
        (const unsigned short*)Sc, 2 * SEQ, (size_t)2 * SEQ * SEQ,
        Vt + (size_t)b0 * DIM * SEQ, SEQ, (size_t)DIM * SEQ,
        Ob + (size_t)b0 * SEQ * DIM, DIM, (size_t)SEQ * DIM, nullptr, SEQ, nullptr, 0);
  }
  gemm8<128, EPI_BIAS_F32><<<dim3(DIM / 128, ROWS / 256, 1), 512, 0, stream>>>(
      Ob, DIM, 0, WoutT, DIM, 0, out, DIM, 0, b_out, DIM, nullptr, 0);
}

// Round 12
// 209.443 us; speedup vs baseline: 1.0237x; 1.0237x over previous
//
#include <hip/hip_runtime.h>
#include <hip/hip_bf16.h>
#include <math.h>

typedef __attribute__((ext_vector_type(8))) __bf16 bf16x8;
typedef __attribute__((ext_vector_type(4))) float f32x4;

#define DIM 1024
#define SEQ 2048
#define BATCH 4
#define ROWS (BATCH*SEQ)

__device__ __forceinline__ unsigned short f2bf(float f) {
  unsigned int u = __float_as_uint(f);
  u += 0x7FFF + ((u >> 16) & 1);   // RNE
  return (unsigned short)(u >> 16);
}

__device__ __forceinline__ void gload_lds16(const void* g, void* lds) {
  __builtin_amdgcn_global_load_lds((__attribute__((address_space(1))) void*)g,
                                   (__attribute__((address_space(3))) void*)lds,
                                   16, 0, 0);
}

// ---------- f32 -> bf16 ----------
__global__ __launch_bounds__(256)
void conv_f32_bf16(const float* __restrict__ src, unsigned short* __restrict__ dst, int n8) {
  int i = blockIdx.x * blockDim.x + threadIdx.x;
  if (i >= n8) return;
  const float4* s = reinterpret_cast<const float4*>(src) + (size_t)i * 2;
  float4 a = s[0], b = s[1];
  union { unsigned short h[8]; uint4 v; } p;
  p.h[0]=f2bf(a.x); p.h[1]=f2bf(a.y); p.h[2]=f2bf(a.z); p.h[3]=f2bf(a.w);
  p.h[4]=f2bf(b.x); p.h[5]=f2bf(b.y); p.h[6]=f2bf(b.z); p.h[7]=f2bf(b.w);
  reinterpret_cast<uint4*>(dst)[i] = p.v;
}

// ---------- merged weight transpose: z=0..2 -> W_in col-chunks, z=3 -> W_out ----------
__global__ __launch_bounds__(1024)
void transpose_weights(const float* __restrict__ W_in, unsigned short* __restrict__ WinT,
                       const float* __restrict__ W_out, unsigned short* __restrict__ WoutT) {
  __shared__ unsigned short tile[32][33];
  const int z = blockIdx.z;
  const float* src; unsigned short* dst; int ldsrc, bx;
  if (z < 3) { src = W_in;  dst = WinT;  ldsrc = 3 * DIM; bx = z * 32 + blockIdx.x; }
  else       { src = W_out; dst = WoutT; ldsrc = DIM;     bx = blockIdx.x; }
  int tx = threadIdx.x, ty = threadIdx.y;
  int r = blockIdx.y * 32 + ty, c = bx * 32 + tx;
  tile[ty][tx] = f2bf(src[(size_t)r * ldsrc + c]);
  __syncthreads();
  dst[(size_t)(bx * 32 + ty) * DIM + blockIdx.y * 32 + tx] = tile[tx][ty];
}

#define EPI_QKV 0
#define EPI_F32 1
#define EPI_BF16 2
#define EPI_BIAS_F32 3

// ---------- m97-archetype NT GEMM: C[M,N] = A[M,K]*B[N,K]^T ----------
// 128x128 tile, BK=64, 4 waves (2x2), per-wave 64x64, 32 KB LDS single-buffer.
// 2 barriers per K-tile; compiler-scheduled ds_reads (counted lgkmcnt
// interleave) and vmcnt(0)-drain at the 2nd barrier; cross-block overlap
// (~3 blocks/CU at ~170 VGPR) hides the drain — the measured-874TF structure.
// XOR swizzle (source pre-swizzle + read XOR) for 0-conflict ds_read_b128.
// EPI_QKV: V-column tiles (tileN>=2*DIM) write transposed directly to Vt.
template<int EPI>
__global__ __launch_bounds__(256, 3)
void gemm97(const unsigned short* __restrict__ A, int lda, size_t sA,
            const unsigned short* __restrict__ B, int ldb, size_t sB,
            void* __restrict__ C, int ldc, size_t sC,
            const float* __restrict__ bias, int K,
            unsigned short* __restrict__ VtOut, size_t sVt) {
  __shared__ unsigned short As[128 * 64];
  __shared__ unsigned short Bs[128 * 64];

  const int tid = threadIdx.x;
  const int lane = tid & 63, wave = tid >> 6;
  const int wr = wave >> 1, wc = wave & 1;
  const int fr = lane & 15, fk = lane >> 4;
  const int tileM = blockIdx.y * 128, tileN = blockIdx.x * 128;
  const unsigned short* Ab = A + (size_t)blockIdx.z * sA;
  const unsigned short* Bb = B + (size_t)blockIdx.z * sB;

  // staging: 256 thr x 16B = 4 KB/round = 32 rows of 128B; 4 rounds per tile.
  const int srow = tid >> 3;                 // 0..31
  const int sg = (tid & 7) ^ (srow & 7);     // pre-swizzled source 16B-chunk
  const int sp = (tid & 7) * 8;              // linear LDS slot (shorts)

  f32x4 acc[4][4];
#pragma unroll
  for (int m = 0; m < 4; ++m)
#pragma unroll
    for (int n = 0; n < 4; ++n) acc[m][n] = (f32x4){0.f, 0.f, 0.f, 0.f};

  for (int kt = 0; kt < K; kt += 64) {
    __syncthreads();                         // prev-tile readers done
#pragma unroll
    for (int q = 0; q < 4; ++q) {
      int rl = q * 32 + srow;
      gload_lds16(Ab + (size_t)(tileM + rl) * lda + kt + sg * 8, &As[rl * 64 + sp]);
    }
#pragma unroll
    for (int q = 0; q < 4; ++q) {
      int rl = q * 32 + srow;
      gload_lds16(Bb + (size_t)(tileN + rl) * ldb + kt + sg * 8, &Bs[rl * 64 + sp]);
    }
    __syncthreads();                         // vmcnt(0) drain (compiler-inserted)

    bf16x8 af[4][2], bg[4][2];
#pragma unroll
    for (int m = 0; m < 4; ++m) {
      int row = wr * 64 + m * 16 + fr;
#pragma unroll
      for (int kk = 0; kk < 2; ++kk)
        af[m][kk] = *reinterpret_cast<const bf16x8*>(
            &As[row * 64 + (((kk * 4 + fk) ^ (row & 7)) << 3)]);
    }
#pragma unroll
    for (int n = 0; n < 4; ++n) {
      int row = wc * 64 + n * 16 + fr;
#pragma unroll
      for (int kk = 0; kk < 2; ++kk)
        bg[n][kk] = *reinterpret_cast<const bf16x8*>(
            &Bs[row * 64 + (((kk * 4 + fk) ^ (row & 7)) << 3)]);
    }
#pragma unroll
    for (int kk = 0; kk < 2; ++kk)
#pragma unroll
      for (int m = 0; m < 4; ++m)
#pragma unroll
        for (int n = 0; n < 4; ++n)
          acc[m][n] = __builtin_amdgcn_mfma_f32_16x16x32_bf16(af[m][kk], bg[n][kk], acc[m][n], 0, 0, 0);
  }

  // ---- epilogue ----
  if (EPI == EPI_QKV && tileN >= 2 * DIM) {
    // V tile: write transposed directly into Vt[d][seq] (j is seq-contiguous)
    const int b = tileM >> 11;               // batch
    const int sb0 = (tileM & (SEQ - 1)) + wr * 64;
    unsigned short* Vb = VtOut + (size_t)b * sVt;
#pragma unroll
    for (int m = 0; m < 4; ++m)
#pragma unroll
      for (int n = 0; n < 4; ++n) {
        int col = tileN + wc * 64 + n * 16 + fr;
        int d = col - 2 * DIM;
        int s = sb0 + m * 16 + fk * 4;
        union { unsigned short h[4]; uint2 u; } p;
#pragma unroll
        for (int j = 0; j < 4; ++j) p.h[j] = f2bf(acc[m][n][j] + bias[col]);
        *reinterpret_cast<uint2*>(&Vb[(size_t)d * SEQ + s]) = p.u;
      }
  } else {
#pragma unroll
    for (int m = 0; m < 4; ++m)
#pragma unroll
      for (int n = 0; n < 4; ++n)
#pragma unroll
        for (int j = 0; j < 4; ++j) {
          int row = tileM + wr * 64 + m * 16 + fk * 4 + j;
          int col = tileN + wc * 64 + n * 16 + fr;
          float v = acc[m][n][j];
          if (EPI == EPI_QKV) {
            v += bias[col];
            if (col < DIM) v *= 0.03125f;    // 1/sqrt(1024)
            ((unsigned short*)C + (size_t)blockIdx.z * sC)[(size_t)row * ldc + col] = f2bf(v);
          } else if (EPI == EPI_BF16) {
            ((unsigned short*)C + (size_t)blockIdx.z * sC)[(size_t)row * ldc + col] = f2bf(v);
          } else if (EPI == EPI_BIAS_F32) {
            ((float*)C + (size_t)blockIdx.z * sC)[(size_t)row * ldc + col] = v + bias[col];
          } else {
            ((float*)C + (size_t)blockIdx.z * sC)[(size_t)row * ldc + col] = v;
          }
        }
  }
}

// ---------- row softmax, in-place: fp32 row -> bf16 P at row start ----------
__global__ __launch_bounds__(256)
void softmax_kernel(float* __restrict__ S, size_t zstride) {
  __shared__ float red[8];
  float* row = S + (size_t)blockIdx.y * zstride + (size_t)blockIdx.x * SEQ;
  const int tid = threadIdx.x;
  const int lane = tid & 63, wave = tid >> 6;
  const float4* src = reinterpret_cast<const float4*>(row) + tid * 2;
  float4 a = src[0], b = src[1];
  float v[8] = {a.x, a.y, a.z, a.w, b.x, b.y, b.z, b.w};
  float m = v[0];
#pragma unroll
  for (int i = 1; i < 8; ++i) m = fmaxf(m, v[i]);
  for (int o = 32; o; o >>= 1) m = fmaxf(m, __shfl_xor(m, o));
  if (lane == 0) red[wave] = m;
  __syncthreads();
  m = fmaxf(fmaxf(red[0], red[1]), fmaxf(red[2], red[3]));
  float e[8], s = 0.f;
#pragma unroll
  for (int i = 0; i < 8; ++i) { e[i] = __expf(v[i] - m); s += e[i]; }
  for (int o = 32; o; o >>= 1) s += __shfl_xor(s, o);
  if (lane == 0) red[4 + wave] = s;
  __syncthreads();
  s = red[4] + red[5] + red[6] + red[7];
  float inv = 1.f / s;
  union { unsigned short h[8]; uint4 u; } p;
#pragma unroll
  for (int i = 0; i < 8; ++i) p.h[i] = f2bf(e[i] * inv);
  reinterpret_cast<uint4*>(row)[tid] = p.u;
}

extern "C" void kernel_launch(void* const* d_in, const int* in_sizes, int n_in,
                              void* d_out, int out_size, void* d_ws, size_t ws_size,
                              hipStream_t stream) {
  const float* X     = (const float*)d_in[0];
  const float* W_in  = (const float*)d_in[1];
  const float* b_in  = (const float*)d_in[2];
  const float* W_out = (const float*)d_in[3];
  const float* b_out = (const float*)d_in[4];
  float* out = (float*)d_out;
  char* ws = (char*)d_ws;

  size_t o = 0;
  auto alloc = [&](size_t bytes) { size_t r = o; o += (bytes + 255) & ~(size_t)255; return r; };
  unsigned short* Xbf   = (unsigned short*)(ws + alloc((size_t)ROWS * DIM * 2));     // aliased as O later
  unsigned short* WinT  = (unsigned short*)(ws + alloc((size_t)3 * DIM * DIM * 2));
  unsigned short* WoutT = (unsigned short*)(ws + alloc((size_t)DIM * DIM * 2));
  unsigned short* QKV   = (unsigned short*)(ws + alloc((size_t)ROWS * 3 * DIM * 2));
  unsigned short* Vt    = (unsigned short*)(ws + alloc((size_t)BATCH * DIM * SEQ * 2)); // QKV fills all batches
  size_t fixed = o;
  size_t per_batch = (((size_t)SEQ * SEQ * 4 + 255) & ~(size_t)255);
  int G = (ws_size >= fixed + 4 * per_batch) ? BATCH : 1;
  float* Sc = (float*)(ws + alloc((size_t)G * SEQ * SEQ * 4));  // P written in place (bf16)
  unsigned short* Ob = Xbf;   // Xbf dead after QKV GEMM

  conv_f32_bf16<<<(ROWS * DIM / 8 + 255) / 256, 256, 0, stream>>>(X, Xbf, ROWS * DIM / 8);
  transpose_weights<<<dim3(32, 32, 4), dim3(32, 32), 0, stream>>>(W_in, WinT, W_out, WoutT);
  // QKV (Q,K into QKV buffer; V transposed directly into Vt): grid 24x64 = 1536
  gemm97<EPI_QKV><<<dim3(3 * DIM / 128, ROWS / 128, 1), 256, 0, stream>>>(
      Xbf, DIM, 0, WinT, DIM, 0, QKV, 3 * DIM, 0, b_in, DIM,
      Vt, (size_t)DIM * SEQ);

  for (int b0 = 0; b0 < BATCH; b0 += G) {
    const unsigned short* Qb = QKV + (size_t)b0 * SEQ * 3 * DIM;
    const unsigned short* Kb = Qb + DIM;
    // scores: grid (16,16,G) = 1024 blocks
    gemm97<EPI_F32><<<dim3(SEQ / 128, SEQ / 128, G), 256, 0, stream>>>(
        Qb, 3 * DIM, (size_t)SEQ * 3 * DIM, Kb, 3 * DIM, (size_t)SEQ * 3 * DIM,
        Sc, SEQ, (size_t)SEQ * SEQ, nullptr, DIM, nullptr, 0);
    softmax_kernel<<<dim3(SEQ, G), 256, 0, stream>>>(Sc, (size_t)SEQ * SEQ);
    // PV: grid (8,16,G) = 512 blocks
    gemm97<EPI_BF16><<<dim3(DIM / 128, SEQ / 128, G), 256, 0, stream>>>(
        (const unsigned short*)Sc, 2 * SEQ, (size_t)2 * SEQ * SEQ,
        Vt + (size_t)b0 * DIM * SEQ, SEQ, (size_t)DIM * SEQ,
        Ob + (size_t)b0 * SEQ * DIM, DIM, (size_t)SEQ * DIM, nullptr, SEQ, nullptr, 0);
  }
  // proj: grid (8,64) = 512 blocks
  gemm97<EPI_BIAS_F32><<<dim3(DIM / 128, ROWS / 128, 1), 256, 0, stream>>>(
      Ob, DIM, 0, WoutT, DIM, 0, out, DIM, 0, b_out, DIM, nullptr, 0);
}

// Round 13
// 203.828 us; speedup vs baseline: 1.0519x; 1.0275x over previous
//
#include <hip/hip_runtime.h>
#include <hip/hip_bf16.h>
#include <math.h>

typedef __attribute__((ext_vector_type(8))) __bf16 bf16x8;
typedef __attribute__((ext_vector_type(4))) float f32x4;

#define DIM 1024
#define SEQ 2048
#define BATCH 4
#define ROWS (BATCH*SEQ)

__device__ __forceinline__ unsigned short f2bf(float f) {
  unsigned int u = __float_as_uint(f);
  u += 0x7FFF + ((u >> 16) & 1);   // RNE
  return (unsigned short)(u >> 16);
}

__device__ __forceinline__ void gload_lds16(const void* g, void* lds) {
  __builtin_amdgcn_global_load_lds((__attribute__((address_space(1))) void*)g,
                                   (__attribute__((address_space(3))) void*)lds,
                                   16, 0, 0);
}

// ---------- f32 -> bf16 ----------
__global__ __launch_bounds__(256)
void conv_f32_bf16(const float* __restrict__ src, unsigned short* __restrict__ dst, int n8) {
  int i = blockIdx.x * blockDim.x + threadIdx.x;
  if (i >= n8) return;
  const float4* s = reinterpret_cast<const float4*>(src) + (size_t)i * 2;
  float4 a = s[0], b = s[1];
  union { unsigned short h[8]; uint4 v; } p;
  p.h[0]=f2bf(a.x); p.h[1]=f2bf(a.y); p.h[2]=f2bf(a.z); p.h[3]=f2bf(a.w);
  p.h[4]=f2bf(b.x); p.h[5]=f2bf(b.y); p.h[6]=f2bf(b.z); p.h[7]=f2bf(b.w);
  reinterpret_cast<uint4*>(dst)[i] = p.v;
}

// ---------- merged weight transpose: z=0..2 -> W_in col-chunks, z=3 -> W_out ----------
__global__ __launch_bounds__(1024)
void transpose_weights(const float* __restrict__ W_in, unsigned short* __restrict__ WinT,
                       const float* __restrict__ W_out, unsigned short* __restrict__ WoutT) {
  __shared__ unsigned short tile[32][33];
  const int z = blockIdx.z;
  const float* src; unsigned short* dst; int ldsrc, bx;
  if (z < 3) { src = W_in;  dst = WinT;  ldsrc = 3 * DIM; bx = z * 32 + blockIdx.x; }
  else       { src = W_out; dst = WoutT; ldsrc = DIM;     bx = blockIdx.x; }
  int tx = threadIdx.x, ty = threadIdx.y;
  int r = blockIdx.y * 32 + ty, c = bx * 32 + tx;
  tile[ty][tx] = f2bf(src[(size_t)r * ldsrc + c]);
  __syncthreads();
  dst[(size_t)(bx * 32 + ty) * DIM + blockIdx.y * 32 + tx] = tile[tx][ty];
}

#define EPI_QKV 0
#define EPI_F32 1
#define EPI_BF16 2
#define EPI_BIAS_F32 3

// ---------- m97-archetype NT GEMM: C[M,N] = A[M,K]*B[N,K]^T ----------
// 128x128 tile, BK=64, 4 waves (2x2), per-wave 64x64, 32 KB LDS single-buffer.
// 2 barriers per K-tile; compiler-scheduled ds_reads; ~3 blocks/CU hide the
// vmcnt(0) drain (measured-874TF structure; QKV hit 799 TF here in r12).
// XOR swizzle (source pre-swizzle + read XOR) for 0-conflict ds_read_b128.
// EPI_QKV: M-fastest grid order (tileM from blockIdx.x) so co-resident blocks
// share one 262KB B-panel in L2 (r12 FETCH showed B thrash at N-fastest).
// EPI_QKV: V-column tiles (tileN>=2*DIM) write transposed directly to Vt.
template<int EPI>
__global__ __launch_bounds__(256, 3)
void gemm97(const unsigned short* __restrict__ A, int lda, size_t sA,
            const unsigned short* __restrict__ B, int ldb, size_t sB,
            void* __restrict__ C, int ldc, size_t sC,
            const float* __restrict__ bias, int K,
            unsigned short* __restrict__ VtOut, size_t sVt) {
  __shared__ unsigned short As[128 * 64];
  __shared__ unsigned short Bs[128 * 64];

  const int tid = threadIdx.x;
  const int lane = tid & 63, wave = tid >> 6;
  const int wr = wave >> 1, wc = wave & 1;
  const int fr = lane & 15, fk = lane >> 4;
  // M-fastest for QKV (B-panel L2 reuse); N-fastest otherwise.
  const int tileM = (EPI == EPI_QKV ? blockIdx.x : blockIdx.y) * 128;
  const int tileN = (EPI == EPI_QKV ? blockIdx.y : blockIdx.x) * 128;
  const unsigned short* Ab = A + (size_t)blockIdx.z * sA;
  const unsigned short* Bb = B + (size_t)blockIdx.z * sB;

  // staging: 256 thr x 16B = 4 KB/round = 32 rows of 128B; 4 rounds per tile.
  const int srow = tid >> 3;                 // 0..31
  const int sg = (tid & 7) ^ (srow & 7);     // pre-swizzled source 16B-chunk
  const int sp = (tid & 7) * 8;              // linear LDS slot (shorts)

  f32x4 acc[4][4];
#pragma unroll
  for (int m = 0; m < 4; ++m)
#pragma unroll
    for (int n = 0; n < 4; ++n) acc[m][n] = (f32x4){0.f, 0.f, 0.f, 0.f};

  for (int kt = 0; kt < K; kt += 64) {
    __syncthreads();                         // prev-tile readers done
#pragma unroll
    for (int q = 0; q < 4; ++q) {
      int rl = q * 32 + srow;
      gload_lds16(Ab + (size_t)(tileM + rl) * lda + kt + sg * 8, &As[rl * 64 + sp]);
    }
#pragma unroll
    for (int q = 0; q < 4; ++q) {
      int rl = q * 32 + srow;
      gload_lds16(Bb + (size_t)(tileN + rl) * ldb + kt + sg * 8, &Bs[rl * 64 + sp]);
    }
    __syncthreads();                         // vmcnt(0) drain (compiler-inserted)

    bf16x8 af[4][2], bg[4][2];
#pragma unroll
    for (int m = 0; m < 4; ++m) {
      int row = wr * 64 + m * 16 + fr;
#pragma unroll
      for (int kk = 0; kk < 2; ++kk)
        af[m][kk] = *reinterpret_cast<const bf16x8*>(
            &As[row * 64 + (((kk * 4 + fk) ^ (row & 7)) << 3)]);
    }
#pragma unroll
    for (int n = 0; n < 4; ++n) {
      int row = wc * 64 + n * 16 + fr;
#pragma unroll
      for (int kk = 0; kk < 2; ++kk)
        bg[n][kk] = *reinterpret_cast<const bf16x8*>(
            &Bs[row * 64 + (((kk * 4 + fk) ^ (row & 7)) << 3)]);
    }
#pragma unroll
    for (int kk = 0; kk < 2; ++kk)
#pragma unroll
      for (int m = 0; m < 4; ++m)
#pragma unroll
        for (int n = 0; n < 4; ++n)
          acc[m][n] = __builtin_amdgcn_mfma_f32_16x16x32_bf16(af[m][kk], bg[n][kk], acc[m][n], 0, 0, 0);
  }

  // ---- epilogue ----
  if (EPI == EPI_QKV && tileN >= 2 * DIM) {
    // V tile: write transposed directly into Vt[d][seq] (j is seq-contiguous)
    const int b = tileM >> 11;               // batch
    const int sb0 = (tileM & (SEQ - 1)) + wr * 64;
    unsigned short* Vb = VtOut + (size_t)b * sVt;
#pragma unroll
    for (int m = 0; m < 4; ++m)
#pragma unroll
      for (int n = 0; n < 4; ++n) {
        int col = tileN + wc * 64 + n * 16 + fr;
        int d = col - 2 * DIM;
        int s = sb0 + m * 16 + fk * 4;
        union { unsigned short h[4]; uint2 u; } p;
#pragma unroll
        for (int j = 0; j < 4; ++j) p.h[j] = f2bf(acc[m][n][j] + bias[col]);
        *reinterpret_cast<uint2*>(&Vb[(size_t)d * SEQ + s]) = p.u;
      }
  } else {
#pragma unroll
    for (int m = 0; m < 4; ++m)
#pragma unroll
      for (int n = 0; n < 4; ++n)
#pragma unroll
        for (int j = 0; j < 4; ++j) {
          int row = tileM + wr * 64 + m * 16 + fk * 4 + j;
          int col = tileN + wc * 64 + n * 16 + fr;
          float v = acc[m][n][j];
          if (EPI == EPI_QKV) {
            v += bias[col];
            if (col < DIM) v *= 0.03125f;    // 1/sqrt(1024)
            ((unsigned short*)C + (size_t)blockIdx.z * sC)[(size_t)row * ldc + col] = f2bf(v);
          } else if (EPI == EPI_BF16) {
            ((unsigned short*)C + (size_t)blockIdx.z * sC)[(size_t)row * ldc + col] = f2bf(v);
          } else if (EPI == EPI_BIAS_F32) {
            ((float*)C + (size_t)blockIdx.z * sC)[(size_t)row * ldc + col] = v + bias[col];
          } else {
            ((float*)C + (size_t)blockIdx.z * sC)[(size_t)row * ldc + col] = v;
          }
        }
  }
}

// ---------- row softmax, in-place: fp32 row -> bf16 P at row start ----------
__global__ __launch_bounds__(256)
void softmax_kernel(float* __restrict__ S, size_t zstride) {
  __shared__ float red[8];
  float* row = S + (size_t)blockIdx.y * zstride + (size_t)blockIdx.x * SEQ;
  const int tid = threadIdx.x;
  const int lane = tid & 63, wave = tid >> 6;
  const float4* src = reinterpret_cast<const float4*>(row) + tid * 2;
  float4 a = src[0], b = src[1];
  float v[8] = {a.x, a.y, a.z, a.w, b.x, b.y, b.z, b.w};
  float m = v[0];
#pragma unroll
  for (int i = 1; i < 8; ++i) m = fmaxf(m, v[i]);
  for (int o = 32; o; o >>= 1) m = fmaxf(m, __shfl_xor(m, o));
  if (lane == 0) red[wave] = m;
  __syncthreads();
  m = fmaxf(fmaxf(red[0], red[1]), fmaxf(red[2], red[3]));
  float e[8], s = 0.f;
#pragma unroll
  for (int i = 0; i < 8; ++i) { e[i] = __expf(v[i] - m); s += e[i]; }
  for (int o = 32; o; o >>= 1) s += __shfl_xor(s, o);
  if (lane == 0) red[4 + wave] = s;
  __syncthreads();
  s = red[4] + red[5] + red[6] + red[7];
  float inv = 1.f / s;
  union { unsigned short h[8]; uint4 u; } p;
#pragma unroll
  for (int i = 0; i < 8; ++i) p.h[i] = f2bf(e[i] * inv);
  reinterpret_cast<uint4*>(row)[tid] = p.u;
}

extern "C" void kernel_launch(void* const* d_in, const int* in_sizes, int n_in,
                              void* d_out, int out_size, void* d_ws, size_t ws_size,
                              hipStream_t stream) {
  const float* X     = (const float*)d_in[0];
  const float* W_in  = (const float*)d_in[1];
  const float* b_in  = (const float*)d_in[2];
  const float* W_out = (const float*)d_in[3];
  const float* b_out = (const float*)d_in[4];
  float* out = (float*)d_out;
  char* ws = (char*)d_ws;

  size_t o = 0;
  auto alloc = [&](size_t bytes) { size_t r = o; o += (bytes + 255) & ~(size_t)255; return r; };
  unsigned short* Xbf   = (unsigned short*)(ws + alloc((size_t)ROWS * DIM * 2));     // aliased as O later
  unsigned short* WinT  = (unsigned short*)(ws + alloc((size_t)3 * DIM * DIM * 2));
  unsigned short* WoutT = (unsigned short*)(ws + alloc((size_t)DIM * DIM * 2));
  unsigned short* QKV   = (unsigned short*)(ws + alloc((size_t)ROWS * 3 * DIM * 2));
  unsigned short* Vt    = (unsigned short*)(ws + alloc((size_t)BATCH * DIM * SEQ * 2)); // QKV fills all batches
  size_t fixed = o;
  size_t per_batch = (((size_t)SEQ * SEQ * 4 + 255) & ~(size_t)255);
  int G = (ws_size >= fixed + 4 * per_batch) ? BATCH : 1;
  float* Sc = (float*)(ws + alloc((size_t)G * SEQ * SEQ * 4));  // P written in place (bf16)
  unsigned short* Ob = Xbf;   // Xbf dead after QKV GEMM

  conv_f32_bf16<<<(ROWS * DIM / 8 + 255) / 256, 256, 0, stream>>>(X, Xbf, ROWS * DIM / 8);
  transpose_weights<<<dim3(32, 32, 4), dim3(32, 32), 0, stream>>>(W_in, WinT, W_out, WoutT);
  // QKV: M-fastest grid (64 M-blocks in x, 24 N-blocks in y) = 1536 blocks
  gemm97<EPI_QKV><<<dim3(ROWS / 128, 3 * DIM / 128, 1), 256, 0, stream>>>(
      Xbf, DIM, 0, WinT, DIM, 0, QKV, 3 * DIM, 0, b_in, DIM,
      Vt, (size_t)DIM * SEQ);

  for (int b0 = 0; b0 < BATCH; b0 += G) {
    const unsigned short* Qb = QKV + (size_t)b0 * SEQ * 3 * DIM;
    const unsigned short* Kb = Qb + DIM;
    // scores: grid (16,16,G) = 1024 blocks
    gemm97<EPI_F32><<<dim3(SEQ / 128, SEQ / 128, G), 256, 0, stream>>>(
        Qb, 3 * DIM, (size_t)SEQ * 3 * DIM, Kb, 3 * DIM, (size_t)SEQ * 3 * DIM,
        Sc, SEQ, (size_t)SEQ * SEQ, nullptr, DIM, nullptr, 0);
    softmax_kernel<<<dim3(SEQ, G), 256, 0, stream>>>(Sc, (size_t)SEQ * SEQ);
    // PV: grid (8,16,G) = 512 blocks
    gemm97<EPI_BF16><<<dim3(DIM / 128, SEQ / 128, G), 256, 0, stream>>>(
        (const unsigned short*)Sc, 2 * SEQ, (size_t)2 * SEQ * SEQ,
        Vt + (size_t)b0 * DIM * SEQ, SEQ, (size_t)DIM * SEQ,
        Ob + (size_t)b0 * SEQ * DIM, DIM, (size_t)SEQ * DIM, nullptr, SEQ, nullptr, 0);
  }
  // proj: grid (8,64) = 512 blocks
  gemm97<EPI_BIAS_F32><<<dim3(DIM / 128, ROWS / 128, 1), 256, 0, stream>>>(
      Ob, DIM, 0, WoutT, DIM, 0, out, DIM, 0, b_out, DIM, nullptr, 0);
}